// Round 11
// baseline (275.866 us; speedup 1.0000x reference)
//
#include <hip/hip_runtime.h>
#include <math.h>

#define N_NODES 100000
#define DIMS 128
#define TS 136      // zs LDS tile stride in halves (272 B)
#define NB_EDGE 2048

typedef _Float16 f16_t;
typedef f16_t f16x8 __attribute__((ext_vector_type(8)));
typedef float f32x4 __attribute__((ext_vector_type(4)));

__device__ __forceinline__ f16x8 cvt8(float4 a, float4 b) {
    f16x8 h = { (f16_t)a.x, (f16_t)a.y, (f16_t)a.z, (f16_t)a.w,
                (f16_t)b.x, (f16_t)b.y, (f16_t)b.z, (f16_t)b.w };
    return h;
}

// Kernel 1: z16 = fp16(z). Pure streaming, fully coalesced.
__global__ __launch_bounds__(256)
void z16_kernel(const float* __restrict__ z, f16_t* __restrict__ z16, int n8) {
    const int i = blockIdx.x * 256 + threadIdx.x;   // chunk of 8 floats
    if (i >= n8) return;
    float4 v0 = *(const float4*)(z + (size_t)i * 8);
    float4 v1 = *(const float4*)(z + (size_t)i * 8 + 4);
    *(f16x8*)(z16 + (size_t)i * 8) = cvt8(v0, v1);
}

// Kernel 2: per-edge recompute. One wave handles 16 edges:
//   wz_tile(16x128) = z16[dst rows] @ W^T + b   via mfma_f32_16x16x32_f16,
//   v[e] = dot(z16[src e], wz_tile[e]),  out[e] = sigmoid(v).
// W fragments persist in registers (8 nt x 4 c x f16x8 = 128 VGPR), loaded
// once per block. zd gathered directly in MFMA A-layout; zs staged through a
// wave-private LDS tile for the C-layout dot. Layouts identical to the
// R7-verified arrangement (A: row=lane&15, k=quad*8+j; C: col=lane&15,
// row=quad*4+reg).
__global__ __launch_bounds__(256, 2)
void edge_mfma_kernel(const f16_t* __restrict__ z16, const float* __restrict__ W,
                      const float* __restrict__ b,
                      const int* __restrict__ src, const int* __restrict__ dst,
                      float* __restrict__ out, int E) {
    __shared__ f16_t zs_l[4][16 * TS];   // 17.4 KB/block, wave-private tiles
    const int t    = threadIdx.x;
    const int lane = t & 63;
    const int wave = t >> 6;
    const int m    = lane & 15;
    const int quad = lane >> 4;

    // Persistent W fragments + bias (amortized over ~12 tiles/block).
    f16x8 bfrag[8][4];
    float bv[8];
    #pragma unroll
    for (int nt = 0; nt < 8; ++nt) {
        const float* wrow = W + (size_t)(nt * 16 + m) * DIMS;
        #pragma unroll
        for (int c = 0; c < 4; ++c) {
            const int k0 = c * 32 + quad * 8;
            float4 w0 = *(const float4*)(wrow + k0);
            float4 w1 = *(const float4*)(wrow + k0 + 4);
            bfrag[nt][c] = cvt8(w0, w1);
        }
        bv[nt] = b[nt * 16 + m];
    }

    f16_t* zsl = zs_l[wave];
    const int ntiles = (E + 15) >> 4;

    for (int tile = blockIdx.x * 4 + wave; tile < ntiles; tile += NB_EDGE * 4) {
        const int e0 = tile * 16;
        int em = e0 + m;
        if (em >= E) em = E - 1;          // clamp (stores masked below)
        const int didx = dst[em];
        const int sidx = src[em];

        // zd: direct gather in A-frag layout (per instr: 16 rows x 64 B).
        f16x8 afrag[4];
        const f16_t* zdrow = z16 + (size_t)didx * DIMS;
        #pragma unroll
        for (int c = 0; c < 4; ++c)
            afrag[c] = *(const f16x8*)(zdrow + c * 32 + quad * 8);

        // zs: stage to LDS row-major (per instr: 4 rows x full 256 B).
        #pragma unroll
        for (int i = 0; i < 4; ++i) {
            const int row  = i * 4 + quad;
            const int ridx = __shfl(sidx, row);
            *(f16x8*)(zsl + row * TS + m * 8) =
                *(const f16x8*)(z16 + (size_t)ridx * DIMS + m * 8);
        }

        // MFMA: acc[nt][r] = b[col] + sum_k zd[row][k] * W[col][k],
        // row = quad*4+r (edge), col = nt*16+m.
        f32x4 acc[8];
        #pragma unroll
        for (int nt = 0; nt < 8; ++nt)
            acc[nt] = (f32x4){bv[nt], bv[nt], bv[nt], bv[nt]};
        #pragma unroll
        for (int nt = 0; nt < 8; ++nt)
            #pragma unroll
            for (int c = 0; c < 4; ++c)
                acc[nt] = __builtin_amdgcn_mfma_f32_16x16x32_f16(
                    afrag[c], bfrag[nt][c], acc[nt], 0, 0, 0);

        // Dot with zs (same-wave ds_write->ds_read: ordered, no barrier).
        float p0 = 0.f, p1 = 0.f, p2 = 0.f, p3 = 0.f;
        #pragma unroll
        for (int nt = 0; nt < 8; ++nt) {
            const int cc = nt * 16 + m;
            p0 += (float)zsl[(quad * 4 + 0) * TS + cc] * acc[nt][0];
            p1 += (float)zsl[(quad * 4 + 1) * TS + cc] * acc[nt][1];
            p2 += (float)zsl[(quad * 4 + 2) * TS + cc] * acc[nt][2];
            p3 += (float)zsl[(quad * 4 + 3) * TS + cc] * acc[nt][3];
        }
        #pragma unroll
        for (int o = 1; o < 16; o <<= 1) {
            p0 += __shfl_xor(p0, o);
            p1 += __shfl_xor(p1, o);
            p2 += __shfl_xor(p2, o);
            p3 += __shfl_xor(p3, o);
        }

        if (m < 4) {
            const int e = e0 + quad * 4 + m;
            const float pv = (m == 0) ? p0 : (m == 1) ? p1 : (m == 2) ? p2 : p3;
            if (e < E)
                out[e] = 1.0f / (1.0f + __expf(-pv));
        }
    }
}

extern "C" void kernel_launch(void* const* d_in, const int* in_sizes, int n_in,
                              void* d_out, int out_size, void* d_ws, size_t ws_size,
                              hipStream_t stream) {
    const float* z  = (const float*)d_in[0];
    const int*   ei = (const int*)d_in[1];   // [2, E] int32
    const float* W  = (const float*)d_in[2];
    const float* b  = (const float*)d_in[3];
    float* out = (float*)d_out;

    const int E = in_sizes[1] / 2;

    f16_t* z16 = (f16_t*)d_ws;               // 25.6 MB

    const int n8 = N_NODES * DIMS / 8;       // 1.6M chunks
    z16_kernel<<<(n8 + 255) / 256, 256, 0, stream>>>(z, z16, n8);

    edge_mfma_kernel<<<NB_EDGE, 256, 0, stream>>>(z16, W, b, ei, ei + E, out, E);
}

// Round 12
// 224.223 us; speedup vs baseline: 1.2303x; 1.2303x over previous
//
#include <hip/hip_runtime.h>
#include <math.h>

#define N_NODES 100000
#define DIMS 128
#define CS 136            // epilogue LDS row stride in halves (272 B)
#define NSTRIPS 6250      // N_NODES / 16 exactly -> no edge guards
#define WZ_BLOCKS 512     // x4 waves = 2048 waves, grid-stride over strips

typedef _Float16 f16_t;
typedef f16_t half4 __attribute__((ext_vector_type(4)));
typedef f16_t f16x8 __attribute__((ext_vector_type(8)));
typedef float f32x4 __attribute__((ext_vector_type(4)));

__device__ __forceinline__ f16x8 cvt8(float4 a, float4 b) {
    f16x8 h = { (f16_t)a.x, (f16_t)a.y, (f16_t)a.z, (f16_t)a.w,
                (f16_t)b.x, (f16_t)b.y, (f16_t)b.z, (f16_t)b.w };
    return h;
}

// wz16 = fp16(z @ W^T + b), z16 = fp16(z), via mfma_f32_16x16x32_f16.
// W lives in REGISTERS (loaded once per wave, amortized over ~3 strips of
// streaming work): no LDS W-staging, no B-frag ds_reads, no __syncthreads.
// Streaming loads are coalesced/predictable, so ~8 waves/CU occupancy is
// enough for full BW (unlike R11's latency-critical gather, where the same
// register footprint was fatal). Layouts = R7/R11-verified.
__global__ __launch_bounds__(256, 2)
void wz_kernel(const float* __restrict__ z, const float* __restrict__ W,
               const float* __restrict__ b,
               f16_t* __restrict__ z16, f16_t* __restrict__ wz16) {
    __shared__ f16_t cl[4][16 * CS];    // 17.4 KB, wave-private epilogue tiles
    const int t    = threadIdx.x;
    const int lane = t & 63;
    const int wave = t >> 6;
    const int m    = lane & 15;
    const int quad = lane >> 4;

    // Persistent W fragments + bias (R11-proven). ~128 VGPR; bias folded
    // into accumulator init.
    f16x8 bfrag[8][4];
    float bv[8];
    #pragma unroll
    for (int nt = 0; nt < 8; ++nt) {
        const float* wrow = W + (size_t)(nt * 16 + m) * DIMS;
        #pragma unroll
        for (int c = 0; c < 4; ++c) {
            const int k0 = c * 32 + quad * 8;
            float4 w0 = *(const float4*)(wrow + k0);
            float4 w1 = *(const float4*)(wrow + k0 + 4);
            bfrag[nt][c] = cvt8(w0, w1);
        }
        bv[nt] = b[nt * 16 + m];
    }

    f16_t* my = cl[wave];
    const int gw = blockIdx.x * 4 + wave;            // 0..2047

    for (int s = gw; s < NSTRIPS; s += WZ_BLOCKS * 4) {
        const int r0   = s * 16;                     // full strip, no guards
        const int arow = r0 + m;

        // A-frags for K=128 (4 chunks of 32), fused z16 emission.
        f16x8 afrag[4];
        #pragma unroll
        for (int c = 0; c < 4; ++c) {
            const int k0 = c * 32 + quad * 8;
            float4 v0 = *(const float4*)(z + (size_t)arow * DIMS + k0);
            float4 v1 = *(const float4*)(z + (size_t)arow * DIMS + k0 + 4);
            afrag[c] = cvt8(v0, v1);
            *(f16x8*)(z16 + (size_t)arow * DIMS + k0) = afrag[c];
        }

        // MFMA: acc[nt][r] = b[col] + sum_k z[row][k]*W[col][k].
        f32x4 acc[8];
        #pragma unroll
        for (int nt = 0; nt < 8; ++nt)
            acc[nt] = (f32x4){bv[nt], bv[nt], bv[nt], bv[nt]};
        #pragma unroll
        for (int nt = 0; nt < 8; ++nt)
            #pragma unroll
            for (int c = 0; c < 4; ++c)
                acc[nt] = __builtin_amdgcn_mfma_f32_16x16x32_f16(
                    afrag[c], bfrag[nt][c], acc[nt], 0, 0, 0);

        // Epilogue: cvt -> wave-local LDS transpose -> coalesced 16B stores.
        // Same-wave ds_write -> ds_read is ordered; cl[wave] is wave-private.
        #pragma unroll
        for (int nt = 0; nt < 8; ++nt)
            #pragma unroll
            for (int r = 0; r < 4; ++r)
                my[(quad * 4 + r) * CS + nt * 16 + m] = (f16_t)acc[nt][r];
        #pragma unroll
        for (int p = 0; p < 4; ++p) {
            const int rr = p * 4 + quad;
            *(f16x8*)(wz16 + (size_t)(r0 + rr) * DIMS + m * 8) =
                *(const f16x8*)(my + rr * CS + m * 8);
        }
    }
}

__device__ __forceinline__ float dot4h(half4 a, half4 w) {
    return fmaf((float)a.x, (float)w.x,
           fmaf((float)a.y, (float)w.y,
           fmaf((float)a.z, (float)w.z, (float)a.w * (float)w.w)));
}

// 4 edges per 32-lane group; fp16 rows (256 B each, 8 B per lane).
// Byte-identical to the proven 105 µs version (R7/R10).
__global__ __launch_bounds__(256)
void edge_kernel(const f16_t* __restrict__ z16, const f16_t* __restrict__ wz16,
                 const int* __restrict__ src, const int* __restrict__ dst,
                 float* __restrict__ out, int E) {
    const int t = blockIdx.x * 256 + threadIdx.x;
    const int g = t >> 5;
    const int l = t & 31;
    const int e0 = g << 2;
    if (e0 >= E) return;

    const int4 s4 = *(const int4*)(src + e0);
    const int4 d4 = *(const int4*)(dst + e0);

    half4 a0 = ((const half4*)(z16  + (size_t)s4.x * DIMS))[l];
    half4 a1 = ((const half4*)(z16  + (size_t)s4.y * DIMS))[l];
    half4 a2 = ((const half4*)(z16  + (size_t)s4.z * DIMS))[l];
    half4 a3 = ((const half4*)(z16  + (size_t)s4.w * DIMS))[l];
    half4 w0 = ((const half4*)(wz16 + (size_t)d4.x * DIMS))[l];
    half4 w1 = ((const half4*)(wz16 + (size_t)d4.y * DIMS))[l];
    half4 w2 = ((const half4*)(wz16 + (size_t)d4.z * DIMS))[l];
    half4 w3 = ((const half4*)(wz16 + (size_t)d4.w * DIMS))[l];

    float p0 = dot4h(a0, w0);
    float p1 = dot4h(a1, w1);
    float p2 = dot4h(a2, w2);
    float p3 = dot4h(a3, w3);

    #pragma unroll
    for (int o = 16; o >= 1; o >>= 1) {
        p0 += __shfl_xor(p0, o);
        p1 += __shfl_xor(p1, o);
        p2 += __shfl_xor(p2, o);
        p3 += __shfl_xor(p3, o);
    }

    if (l == 0) {
        float4 r;
        r.x = 1.0f / (1.0f + __expf(-p0));
        r.y = 1.0f / (1.0f + __expf(-p1));
        r.z = 1.0f / (1.0f + __expf(-p2));
        r.w = 1.0f / (1.0f + __expf(-p3));
        *(float4*)(out + e0) = r;
    }
}

extern "C" void kernel_launch(void* const* d_in, const int* in_sizes, int n_in,
                              void* d_out, int out_size, void* d_ws, size_t ws_size,
                              hipStream_t stream) {
    const float* z  = (const float*)d_in[0];
    const int*   ei = (const int*)d_in[1];   // [2, E] int32
    const float* W  = (const float*)d_in[2];
    const float* b  = (const float*)d_in[3];
    float* out = (float*)d_out;

    const int E = in_sizes[1] / 2;

    f16_t* z16  = (f16_t*)d_ws;                                       // 25.6 MB
    f16_t* wz16 = (f16_t*)((char*)d_ws + (size_t)N_NODES * DIMS * 2); // 25.6 MB

    wz_kernel<<<WZ_BLOCKS, 256, 0, stream>>>(z, W, b, z16, wz16);

    const int groups = (E + 3) / 4;                 // 400000 (E % 4 == 0)
    const int total  = groups * 32;
    edge_kernel<<<(total + 255) / 256, 256, 0, stream>>>(z16, wz16, ei, ei + E, out, E);
}